// Round 3
// baseline (723.430 us; speedup 1.0000x reference)
//
#include <hip/hip_runtime.h>
#include <hip/hip_cooperative_groups.h>
namespace cg = cooperative_groups;

// ---------------- constants ----------------
#define NROWS 16384
#define NF 39
#define NV 100000
#define NE 16
#define HID 400
#define K1 624       // real K of layer 1 (39*16)
#define K1T 640      // padded K span for layer 1
#define K2T 448      // padded K span for layers 2/3 (real 400)
#define BN_EPS 1e-5f

#define RPB 64       // rows per block (grid = 16384/64 = 256 = 1 block/CU)
#define BN_ 448      // full padded output width per block
#define BKF 32       // K-step
#define ASTR 640     // A row stride in ushorts

#define W1E (448 * 640)
#define W2E (448 * 448)
#define TCVT (W1E + 2 * W2E)     // 688128 elems = 86016 chunks; 336 chunks/block

typedef short short8v __attribute__((ext_vector_type(8)));
typedef short short4v __attribute__((ext_vector_type(4)));
typedef float float4v __attribute__((ext_vector_type(4)));

__device__ __forceinline__ float bf2f(unsigned short u) {
    return __uint_as_float(((unsigned int)u) << 16);
}
__device__ __forceinline__ unsigned short f2bf(float f) {
    unsigned int x = __float_as_uint(f);
    return (unsigned short)((x + 0x7FFFu + ((x >> 16) & 1u)) >> 16);
}
__device__ __forceinline__ void gload16(const unsigned short* g, unsigned short* l) {
    __builtin_amdgcn_global_load_lds(
        (const __attribute__((address_space(1))) unsigned int*)g,
        (__attribute__((address_space(3))) unsigned int*)l,
        16, 0, 0);
}

// One cooperative kernel: embed -> gemm1 -> BN1 -> gemm2 -> BN2 -> gemm3 -> BN3+rowsum.
// Activations never leave the block (LDS A-panel / registers); only 800-float BN stats
// cross blocks per layer (device atomics + grid.sync).
__global__ __launch_bounds__(512, 2) void fused_kernel(
    const int* __restrict__ Xi, const float* __restrict__ Xv,
    const float* __restrict__ emb1, const float* __restrict__ emb2,
    const float* __restrict__ W1, const float* __restrict__ W2, const float* __restrict__ W3,
    const float* __restrict__ b1, const float* __restrict__ g1, const float* __restrict__ bt1,
    const float* __restrict__ b2, const float* __restrict__ g2, const float* __restrict__ bt2,
    const float* __restrict__ b3, const float* __restrict__ g3, const float* __restrict__ bt3,
    const float* __restrict__ bias0,
    unsigned short* __restrict__ w1b, unsigned short* __restrict__ w2b,
    unsigned short* __restrict__ w3b,
    float* __restrict__ sums,          // 3 x 800
    float* __restrict__ out)
{
    __shared__ __align__(16) unsigned short As[RPB * ASTR];        // 81920 B
    __shared__ __align__(16) unsigned short Bs[2][BN_ * BKF];      // 57344 B
    __shared__ float ssc[BN_], ssh[BN_], sbias[BN_];
    __shared__ float scol[BN_], qcol[BN_];
    __shared__ float f12s[RPB];
    __shared__ float rowacc[RPB];

    cg::grid_group grid = cg::this_grid();
    int tid = threadIdx.x;
    int lane = tid & 63;
    int wave = tid >> 6;
    int quad = lane >> 4, l16 = lane & 15;
    int mi = wave >> 2;        // 0..1  (rows mi*32)
    int nj = wave & 3;         // 0..3  (cols nj*112)
    int m0 = blockIdx.x * RPB;
    int wbase = tid & ~63;
    float* sums1 = sums;
    float* sums2 = sums + 800;
    float* sums3 = sums + 1600;

    // ---------- phase 0a: weight convert (336 chunks/block) + zero sums ----------
    if (tid < 336) {
        int e = (blockIdx.x * 336 + tid) * 8;
        const float* W; unsigned short* O; int Kreal, Kt, base;
        if (e < W1E)            { W = W1; O = w1b; Kreal = K1;  Kt = K1T; base = 0; }
        else if (e < W1E + W2E) { W = W2; O = w2b; Kreal = HID; Kt = K2T; base = W1E; }
        else                    { W = W3; O = w3b; Kreal = HID; Kt = K2T; base = W1E + W2E; }
        int le = e - base;
        int r = le / Kt, k = le % Kt;
        short8v o;
        #pragma unroll
        for (int ee = 0; ee < 8; ++ee) {
            int kk = k + ee;
            o[ee] = (r < HID && kk < Kreal) ? (short)f2bf(W[(size_t)r * Kreal + kk]) : (short)0;
        }
        *(short8v*)(O + (size_t)r * Kt + k) = o;
    }
    if (blockIdx.x == 0) {
        for (int i = tid; i < 2400; i += 512)
            __hip_atomic_store(&sums[i], 0.f, __ATOMIC_RELAXED, __HIP_MEMORY_SCOPE_AGENT);
    }

    // ---------- phase 0b: embed 64 rows into LDS A-panel (swizzled bf16) ----------
    // NOTE (R2 bug fix): the reference norm is PER embedding dim e:
    //   norm[n,e] = sqrt(sum_f xv[n,f,e]^2).  16 norms per row, not one.
    // Each 16-lane group handles one row; lane lg always touches component quarter
    // q = lg&3 (since (lg+16t)&3 == lg&3), i.e. e = q*4+j, j=0..3.  So per-lane
    // ss/sm[4] + xor-4/8 butterfly (f-partition) give complete per-e sums.
    {
        int* sidx2 = (int*)&Bs[0][0];                   // [32][40]
        float* sxv2 = (float*)&Bs[0][0] + 32 * 40;      // [32][40]
        const float4* e2 = (const float4*)emb2;
        int rl = tid >> 4;          // local row slot 0..31
        int lg = tid & 15;
        int q = lg & 3;
        for (int batch = 0; batch < 2; ++batch) {
            int row = batch * 32 + rl;
            int n = m0 + row;
            #pragma unroll
            for (int t = 0; t < 3; ++t) {
                int f = lg + 16 * t;
                if (f < NF) {
                    sidx2[rl * 40 + f] = Xi[(size_t)n * NF + f];
                    sxv2[rl * 40 + f] = Xv[(size_t)n * NF + f];
                }
            }
            // pass 1: per-e ss/sm, plus f1 (independent gathers in flight)
            float ssA[4] = {0.f, 0.f, 0.f, 0.f};
            float smA[4] = {0.f, 0.f, 0.f, 0.f};
            float f1 = 0.f;
            #pragma unroll
            for (int t = 0; t < 10; ++t) {
                int i = lg + 16 * t;
                if (i < NF * 4) {
                    int f = i >> 2;
                    int idx = sidx2[rl * 40 + f];
                    float xv = sxv2[rl * 40 + f];
                    float4 v = e2[((size_t)f * NV + (size_t)idx) * 4 + q];
                    float p0 = v.x * xv, p1 = v.y * xv, p2 = v.z * xv, p3 = v.w * xv;
                    ssA[0] += p0 * p0; ssA[1] += p1 * p1;
                    ssA[2] += p2 * p2; ssA[3] += p3 * p3;
                    smA[0] += p0; smA[1] += p1; smA[2] += p2; smA[3] += p3;
                }
            }
            #pragma unroll
            for (int t = 0; t < 3; ++t) {
                int f = lg + 16 * t;
                if (f < NF)
                    f1 += emb1[(size_t)f * NV + (size_t)sidx2[rl * 40 + f]] * sxv2[rl * 40 + f];
            }
            // reduce over the f-partition lanes (bits 2,3 of lg)
            #pragma unroll
            for (int j = 0; j < 4; ++j) {
                ssA[j] += __shfl_xor(ssA[j], 4, 16);
                ssA[j] += __shfl_xor(ssA[j], 8, 16);
                smA[j] += __shfl_xor(smA[j], 4, 16);
                smA[j] += __shfl_xor(smA[j], 8, 16);
            }
            float rn4[4];
            float f2p = 0.f;
            #pragma unroll
            for (int j = 0; j < 4; ++j) {
                rn4[j] = 1.f / fmaxf(sqrtf(ssA[j]), 1e-12f);
                float s1 = smA[j] * rn4[j];
                f2p += 0.5f * (s1 * s1 - ssA[j] * rn4[j] * rn4[j]);
            }
            // sum f2 across the 4 q-groups (values uniform within each q-group)
            f2p += __shfl_xor(f2p, 1, 16);
            f2p += __shfl_xor(f2p, 2, 16);
            #pragma unroll
            for (int o = 1; o < 16; o <<= 1) f1 += __shfl_xor(f1, o, 16);
            if (lg == 0) f12s[row] = f1 + f2p;
            // pass 2: re-gather (L1/L2-hot), per-e normalize, bf16, swizzled LDS write
            #pragma unroll
            for (int t = 0; t < 10; ++t) {
                int i = lg + 16 * t;
                if (i < NF * 4) {
                    int f = i >> 2;
                    int idx = sidx2[rl * 40 + f];
                    float xv = sxv2[rl * 40 + f];
                    float4 v = e2[((size_t)f * NV + (size_t)idx) * 4 + q];
                    short4v pk;
                    pk[0] = (short)f2bf((v.x * xv) * rn4[0]);
                    pk[1] = (short)f2bf((v.y * xv) * rn4[1]);
                    pk[2] = (short)f2bf((v.z * xv) * rn4[2]);
                    pk[3] = (short)f2bf((v.w * xv) * rn4[3]);
                    int k0 = f * 16 + q * 4;
                    int c = k0 >> 3;
                    int cs = (c & ~7) | ((c ^ row) & 7);
                    *(short4v*)(As + row * ASTR + cs * 8 + (q & 1) * 4) = pk;
                }
            }
            if (lg < 2) {   // zero chunks 78,79 (cols 624..639)
                int c = 78 + lg;
                int cs = (c & ~7) | ((c ^ row) & 7);
                *(short8v*)(As + row * ASTR + cs * 8) = (short8v){0,0,0,0,0,0,0,0};
            }
        }
    }
    __threadfence();
    grid.sync();    // weights + zeroed sums visible; embed (block-local) done

    // ---------- GEMM machinery ----------
    float4v acc[2][7];
    #pragma unroll
    for (int i = 0; i < 2; ++i)
        #pragma unroll
        for (int f = 0; f < 7; ++f)
            acc[i][f] = (float4v){0.f, 0.f, 0.f, 0.f};

    auto stageB = [&](const unsigned short* Wp, int Kt, int buf, int kt) {
        #pragma unroll
        for (int i2 = 0; i2 < 4; ++i2) {
            int v = tid + i2 * 512;
            if (v < BN_ * 4) {                     // wave-uniform boundary (1792 = 28*64)
                int r = v >> 2, c = v & 3;
                int key = (r >> 1) & 3;            // read-side XOR key (inverse-swz source)
                gload16(Wp + (size_t)r * Kt + kt + (size_t)((c ^ key) * 8),
                        &Bs[buf][(i2 * 512 + wbase) * 8]);
            }
        }
    };
    auto mma_step = [&](int buf, int s) {
        short8v af[2], bfr[7];
        #pragma unroll
        for (int i = 0; i < 2; ++i) {
            int r = mi * 32 + i * 16 + l16;
            int c = s * 4 + quad;
            int cs = (c & ~7) | ((c ^ r) & 7);
            af[i] = *(const short8v*)(As + r * ASTR + cs * 8);
        }
        #pragma unroll
        for (int f = 0; f < 7; ++f) {
            int r = nj * 112 + f * 16 + l16;
            int key = (r >> 1) & 3;
            bfr[f] = *(const short8v*)(&Bs[buf][r * BKF + (quad ^ key) * 8]);
        }
        #pragma unroll
        for (int i = 0; i < 2; ++i)
            #pragma unroll
            for (int f = 0; f < 7; ++f)
                acc[i][f] = __builtin_amdgcn_mfma_f32_16x16x32_bf16(af[i], bfr[f], acc[i][f], 0, 0, 0);
    };
    auto run_layer = [&](const unsigned short* Wp, int Kt, int nsteps) {
        stageB(Wp, Kt, 0, 0);
        __syncthreads();
        for (int s = 0; s < nsteps; ++s) {
            if (s + 1 < nsteps) stageB(Wp, Kt, (s + 1) & 1, (s + 1) * BKF);
            __builtin_amdgcn_s_setprio(1);
            mma_step(s & 1, s);
            __builtin_amdgcn_s_setprio(0);
            __syncthreads();
        }
    };
    auto stats = [&](const float* bv, float* sums_l) {
        if (tid < BN_) { scol[tid] = 0.f; qcol[tid] = 0.f; }
        __syncthreads();
        #pragma unroll
        for (int f = 0; f < 7; ++f) {
            int lc = nj * 112 + f * 16 + l16;
            float bvv = (lc < HID) ? bv[lc] : 0.f;
            float s = 0.f, q = 0.f;
            #pragma unroll
            for (int i = 0; i < 2; ++i)
                #pragma unroll
                for (int r = 0; r < 4; ++r) {
                    float v = acc[i][f][r] + bvv;
                    s += v; q += v * v;
                }
            s += __shfl_down(s, 32, 64); s += __shfl_down(s, 16, 64);
            q += __shfl_down(q, 32, 64); q += __shfl_down(q, 16, 64);
            if (lane < 16) { atomicAdd(&scol[lc], s); atomicAdd(&qcol[lc], q); }
        }
        __syncthreads();
        if (tid < HID) {
            atomicAdd(&sums_l[tid], scol[tid]);
            atomicAdd(&sums_l[HID + tid], qcol[tid]);
        }
        __threadfence();
    };
    auto bn_prepare = [&](const float* sums_l, const float* gv, const float* btv, const float* bv) {
        if (tid < BN_) {
            float sc = 0.f, sh = 0.f, bb = 0.f;
            if (tid < HID) {
                const float invN = 1.f / (float)NROWS;
                float s = __hip_atomic_load(&sums_l[tid], __ATOMIC_RELAXED, __HIP_MEMORY_SCOPE_AGENT);
                float q = __hip_atomic_load(&sums_l[HID + tid], __ATOMIC_RELAXED, __HIP_MEMORY_SCOPE_AGENT);
                float mu = s * invN;
                float var = q * invN - mu * mu;
                float rstd = rsqrtf(var + BN_EPS);
                sc = gv[tid] * rstd;
                sh = btv[tid] - mu * sc;
                bb = bv[tid];
            }
            ssc[tid] = sc; ssh[tid] = sh; sbias[tid] = bb;
        }
        __syncthreads();
    };
    auto bn_apply_to_As = [&]() {
        #pragma unroll
        for (int i = 0; i < 2; ++i)
            #pragma unroll
            for (int f = 0; f < 7; ++f) {
                int col = nj * 112 + f * 16 + l16;
                float sc = ssc[col], sh = ssh[col], bb = sbias[col];
                #pragma unroll
                for (int r = 0; r < 4; ++r) {
                    int row = mi * 32 + i * 16 + quad * 4 + r;
                    float y = fmaxf(sc * (acc[i][f][r] + bb) + sh, 0.f);
                    int c = col >> 3;
                    int cs = (c & ~7) | ((c ^ row) & 7);
                    As[row * ASTR + cs * 8 + (col & 7)] = f2bf(y);
                }
                acc[i][f] = (float4v){0.f, 0.f, 0.f, 0.f};
            }
        __syncthreads();
    };

    // ---------- layer 1 ----------
    run_layer(w1b, K1T, K1T / BKF);     // 20 steps
    stats(b1, sums1);
    grid.sync();
    bn_prepare(sums1, g1, bt1, b1);
    bn_apply_to_As();

    // ---------- layer 2 ----------
    run_layer(w2b, K2T, K2T / BKF);     // 14 steps
    stats(b2, sums2);
    grid.sync();
    bn_prepare(sums2, g2, bt2, b2);
    bn_apply_to_As();

    // ---------- layer 3 ----------
    run_layer(w3b, K2T, K2T / BKF);
    stats(b3, sums3);
    grid.sync();
    bn_prepare(sums3, g3, bt3, b3);

    // ---------- final: BN3 + ReLU + rowsum (in-register) ----------
    if (tid < RPB) rowacc[tid] = 0.f;
    __syncthreads();
    #pragma unroll
    for (int i = 0; i < 2; ++i) {
        float rsum[4] = {0.f, 0.f, 0.f, 0.f};
        #pragma unroll
        for (int f = 0; f < 7; ++f) {
            int col = nj * 112 + f * 16 + l16;
            float sc = ssc[col], sh = ssh[col], bb = sbias[col];
            #pragma unroll
            for (int r = 0; r < 4; ++r)
                rsum[r] += fmaxf(sc * (acc[i][f][r] + bb) + sh, 0.f);
        }
        #pragma unroll
        for (int r = 0; r < 4; ++r) {
            rsum[r] += __shfl_xor(rsum[r], 1, 16);
            rsum[r] += __shfl_xor(rsum[r], 2, 16);
            rsum[r] += __shfl_xor(rsum[r], 4, 16);
            rsum[r] += __shfl_xor(rsum[r], 8, 16);
            if (l16 == 0) {
                int row = mi * 32 + i * 16 + quad * 4 + r;
                atomicAdd(&rowacc[row], rsum[r]);
            }
        }
    }
    __syncthreads();
    if (tid < RPB) out[m0 + tid] = rowacc[tid] + f12s[tid] + bias0[0];
}

// ---------------- launch ----------------
extern "C" void kernel_launch(void* const* d_in, const int* in_sizes, int n_in,
                              void* d_out, int out_size, void* d_ws, size_t ws_size,
                              hipStream_t stream) {
    const int* Xi = (const int*)d_in[0];
    const float* Xv = (const float*)d_in[1];
    const float* emb1 = (const float*)d_in[2];
    const float* emb2 = (const float*)d_in[3];
    const float* W1 = (const float*)d_in[4];
    const float* b1 = (const float*)d_in[5];
    const float* g1 = (const float*)d_in[6];
    const float* bt1 = (const float*)d_in[7];
    const float* W2 = (const float*)d_in[8];
    const float* b2 = (const float*)d_in[9];
    const float* g2 = (const float*)d_in[10];
    const float* bt2 = (const float*)d_in[11];
    const float* W3 = (const float*)d_in[12];
    const float* b3 = (const float*)d_in[13];
    const float* g3 = (const float*)d_in[14];
    const float* bt3 = (const float*)d_in[15];
    const float* bias = (const float*)d_in[16];

    char* ws = (char*)d_ws;
    unsigned short* w1b = (unsigned short*)ws;                 // 448 x 640
    unsigned short* w2b = w1b + (size_t)448 * K1T;             // 448 x 448
    unsigned short* w3b = w2b + (size_t)448 * K2T;             // 448 x 448
    float* sums = (float*)(w3b + (size_t)448 * K2T);           // 3 x 800
    float* out = (float*)d_out;

    void* args[] = {
        (void*)&Xi, (void*)&Xv, (void*)&emb1, (void*)&emb2,
        (void*)&W1, (void*)&W2, (void*)&W3,
        (void*)&b1, (void*)&g1, (void*)&bt1,
        (void*)&b2, (void*)&g2, (void*)&bt2,
        (void*)&b3, (void*)&g3, (void*)&bt3,
        (void*)&bias,
        (void*)&w1b, (void*)&w2b, (void*)&w3b,
        (void*)&sums, (void*)&out
    };
    hipLaunchCooperativeKernel((const void*)fused_kernel, dim3(256), dim3(512),
                               args, 0, stream);
}

// Round 4
// 416.166 us; speedup vs baseline: 1.7383x; 1.7383x over previous
//
#include <hip/hip_runtime.h>

// ---------------- constants ----------------
#define NROWS 16384
#define NF 39
#define NV 100000
#define NE 16
#define HID 400
#define K1 624     // real K of layer 1 (39*16)
#define K1T 640    // padded K span for layer 1 (h0 zero-padded to this)
#define K2T 448    // padded K span for layers 2/3 (real 400)
#define BN_EPS 1e-5f

typedef short short8v __attribute__((ext_vector_type(8)));
typedef float float4v __attribute__((ext_vector_type(4)));

__device__ __forceinline__ float bf2f(unsigned short u) {
    unsigned int x = ((unsigned int)u) << 16;
    return __uint_as_float(x);
}
__device__ __forceinline__ unsigned short f2bf(float f) {
    unsigned int x = __float_as_uint(f);
    unsigned int r = (x + 0x7FFFu + ((x >> 16) & 1u)) >> 16;
    return (unsigned short)r;
}

// async global->LDS DMA, 16B per lane. LDS dest is wave-uniform base + lane*16.
__device__ __forceinline__ void gload16(const unsigned short* g, unsigned short* l) {
    __builtin_amdgcn_global_load_lds(
        (const __attribute__((address_space(1))) unsigned int*)g,
        (__attribute__((address_space(3))) unsigned int*)l,
        16, 0, 0);
}

// Counted-wait barriers (T4-lite). Raw s_barrier: does NOT auto-drain counters,
// so the 6 next-tile loads stay in flight across the MFMA phase.
__device__ __forceinline__ void bar_vm6() {
    asm volatile("s_waitcnt vmcnt(6) lgkmcnt(0)" ::: "memory");
    __builtin_amdgcn_s_barrier();
    __builtin_amdgcn_sched_barrier(0);
}
__device__ __forceinline__ void bar_vm0() {
    asm volatile("s_waitcnt vmcnt(0) lgkmcnt(0)" ::: "memory");
    __builtin_amdgcn_s_barrier();
    __builtin_amdgcn_sched_barrier(0);
}
__device__ __forceinline__ void bar_lgkm() {
    asm volatile("s_waitcnt lgkmcnt(0)" ::: "memory");
    __builtin_amdgcn_s_barrier();
    __builtin_amdgcn_sched_barrier(0);
}

// ---------------- prep: embed (blocks 0..4095) + weight-convert + zero sums -------------
#define EMB_BLOCKS 4096
#define W1E (448 * 640)           // 286720
#define W2E (448 * 448)           // 200704
#define TCVT (W1E + 2 * W2E)      // 688128 elems
#define CVT_BLOCKS (TCVT / 8 / 256)   // 336

__global__ __launch_bounds__(256) void prep_kernel(const int* __restrict__ Xi,
                                                   const float* __restrict__ Xv,
                                                   const float* __restrict__ emb1,
                                                   const float* __restrict__ emb2,
                                                   const float* __restrict__ W1,
                                                   const float* __restrict__ W2,
                                                   const float* __restrict__ W3,
                                                   unsigned short* __restrict__ h0,
                                                   float* __restrict__ f12,
                                                   unsigned short* __restrict__ w1b,
                                                   unsigned short* __restrict__ w2b,
                                                   unsigned short* __restrict__ w3b,
                                                   float* __restrict__ sums) {
    int b = blockIdx.x;
    int tid = threadIdx.x;
    if (b < EMB_BLOCKS) {
        int wave = tid >> 6, lane = tid & 63;
        int n = b * 4 + wave;
        __shared__ int sidx[4][NF + 1];
        __shared__ float sxv[4][NF + 1];
        __shared__ __align__(16) float sx[4][NF * NE];
        __shared__ float srn[4][NE];
        // Load Xi/Xv to regs, publish to LDS, and ISSUE the emb1 gather immediately
        // (it's independent of everything; previously it sat behind the emb2 phase).
        int myidx = 0; float myxv = 0.f, e1v = 0.f;
        if (lane < NF) {
            myidx = Xi[n * NF + lane];
            myxv = Xv[n * NF + lane];
            sidx[wave][lane] = myidx;
            sxv[wave][lane] = myxv;
            e1v = emb1[(size_t)lane * NV + (size_t)myidx];   // long-latency, in flight
        }
        __syncthreads();
        const float4* e2 = (const float4*)emb2;
        // prefetch all (<=3) emb2 gathers to regs before any LDS store -> full MLP
        float4 vv[3];
        float mm[3];
        int ii[3];
        #pragma unroll
        for (int t = 0; t < 3; ++t) {
            int i = lane + 64 * t;
            ii[t] = i;
            if (i < NF * 4) {
                int f = i >> 2, q = i & 3;
                vv[t] = e2[((size_t)f * NV + (size_t)sidx[wave][f]) * 4 + q];
                mm[t] = sxv[wave][f];
            }
        }
        #pragma unroll
        for (int t = 0; t < 3; ++t) {
            int i = ii[t];
            if (i < NF * 4) {
                int f = i >> 2, q = i & 3;
                float4 v = vv[t];
                float m = mm[t];
                float4 o; o.x = v.x * m; o.y = v.y * m; o.z = v.z * m; o.w = v.w * m;
                *(float4*)&sx[wave][f * NE + q * 4] = o;
            }
        }
        __syncthreads();
        float f2 = 0.f;
        if (lane < NE) {
            float ss = 0.f, sm = 0.f;
            #pragma unroll
            for (int f = 0; f < NF; ++f) {
                float v = sx[wave][f * NE + lane];
                ss += v * v;
                sm += v;
            }
            float rn = 1.f / fmaxf(sqrtf(ss), 1e-12f);
            srn[wave][lane] = rn;
            float s = sm * rn;
            f2 = 0.5f * (s * s - ss * rn * rn);
        }
        float f1 = (lane < NF) ? e1v * myxv : 0.f;
        float tot = f1 + f2;
        #pragma unroll
        for (int o = 32; o; o >>= 1) tot += __shfl_down(tot, o, 64);
        if (lane == 0) f12[n] = tot;
        __syncthreads();
        // h0 store: 80 vec8 chunks per row (zero-padded to K1T=640).
        for (int i = lane; i < 80; i += 64) {
            int k0 = i * 8;
            short8v o = (short8v){0, 0, 0, 0, 0, 0, 0, 0};
            if (i < 78) {
                #pragma unroll
                for (int e = 0; e < 8; ++e) {
                    int k = k0 + e;
                    o[e] = (short)f2bf(sx[wave][k] * srn[wave][k & 15]);
                }
            }
            *(short8v*)(h0 + (size_t)n * K1T + k0) = o;
        }
        return;
    }
    b -= EMB_BLOCKS;
    if (b < CVT_BLOCKS) {
        int gidx = b * 256 + tid;
        int e = gidx * 8;
        if (e < TCVT) {
            const float* W; unsigned short* O; int Kreal, Kt, base;
            if (e < W1E) { W = W1; O = w1b; Kreal = K1; Kt = K1T; base = 0; }
            else if (e < W1E + W2E) { W = W2; O = w2b; Kreal = HID; Kt = K2T; base = W1E; }
            else { W = W3; O = w3b; Kreal = HID; Kt = K2T; base = W1E + W2E; }
            int le = e - base;
            int r = le / Kt, k = le % Kt;
            short8v o;
            #pragma unroll
            for (int ee = 0; ee < 8; ++ee) {
                int kk = k + ee;
                o[ee] = (r < HID && kk < Kreal) ? (short)f2bf(W[(size_t)r * Kreal + kk]) : (short)0;
            }
            *(short8v*)(O + (size_t)r * Kt + k) = o;
        }
        return;
    }
    for (int i = tid; i < 2400; i += 256) sums[i] = 0.f;
}

// ---------------- bf16 MFMA GEMM: 512 thr, BM=128, BNT=224 ----------------------------
// v3: counted-vmcnt pipeline. Per K-step every wave issues EXACTLY 6 VMEM ops
// (A: 2 DMA or 2 reg-loads; B: 4 DMA — waves 4..7 re-issue their i2=0 chunk as a
// benign identical-data dummy to equalize). Barrier #1 waits vmcnt(6): drains the
// PREVIOUS step's 6, leaves this step's 6 in flight under the MFMA phase.
// Hazards: stage(buf^1)@s vs mma-readers of buf^1@s-1 separated by barrier#2@s-1;
// buf's staging published at barrier#1@s; writeA_lds(buf^1)@s (LDS) published at
// barrier#2@s (lgkmcnt(0) only — no vmcnt drain).
#define BM 128
#define BNT 224
#define BK 64

template <bool FUSE_BN>
__global__ __launch_bounds__(512, 2) void gemm_kernel(const unsigned short* __restrict__ A,
                                                      int lda, int Kreal, int Kt,
                                                      const unsigned short* __restrict__ W,  // 448 x Kt
                                                      const float* __restrict__ bias,
                                                      const float* __restrict__ psums,
                                                      const float* __restrict__ g,
                                                      const float* __restrict__ bt,
                                                      unsigned short* __restrict__ C,        // ldc = 400
                                                      float* __restrict__ sums) {
    __shared__ __align__(16) unsigned short As[2][BM * BK];    // 2 x 16 KB
    __shared__ __align__(16) unsigned short Bs[2][BNT * BK];   // 2 x 28 KB
    __shared__ float ssc[K2T], ssh[K2T];
    __shared__ float scol[BNT], qcol[BNT];
    int tid = threadIdx.x;
    int wave = tid >> 6, lane = tid & 63;
    int quad = lane >> 4, l16 = lane & 15;
    int mi = wave & 3, nj = wave >> 2;
    int m0 = blockIdx.x * BM;
    int n0 = blockIdx.y * BNT;
    int wbase = tid & ~63;   // wave*64

    if (FUSE_BN && tid < K2T) {
        float sc = 0.f, sh = 0.f;
        if (tid < HID) {
            const float invN = 1.f / (float)NROWS;
            float mu = psums[tid] * invN;
            float var = psums[HID + tid] * invN - mu * mu;
            float rstd = rsqrtf(var + BN_EPS);
            sc = g[tid] * rstd;
            sh = bt[tid] - mu * sc;
        }
        ssc[tid] = sc; ssh[tid] = sh;
    }
    if (tid < BNT) { scol[tid] = 0.f; qcol[tid] = 0.f; }

    const short8v zero8 = (short8v){0, 0, 0, 0, 0, 0, 0, 0};
    short8v Ar[2];

    // layer-1 A staging: async DMA, inverse-swizzled global source (2 loads/thread)
    auto stageA_g = [&](int buf, int kt) {
        #pragma unroll
        for (int i = 0; i < 2; ++i) {
            int v = tid + i * 512;
            int r = v >> 3, c = v & 7;
            int sc = c ^ (r & 7);
            gload16(A + (size_t)(m0 + r) * lda + kt + sc * 8,
                    &As[buf][(size_t)(i * 512 + wbase) * 8]);
        }
    };
    // B staging: async DMA; equalized to exactly 4 loads/thread (waves 4..7 re-issue
    // their i2=0 chunk: same source, same dest, identical bytes -> race-free dummy).
    auto stageB = [&](int buf, int kt) {
        #pragma unroll
        for (int i2 = 0; i2 < 4; ++i2) {
            int v = tid + i2 * 512;
            int vv = (v < BNT * 8) ? v : tid;
            int dst = (v < BNT * 8) ? (i2 * 512 + wbase) : wbase;
            int r = vv >> 3, c = vv & 7;
            int sc = c ^ (r & 7);
            gload16(W + (size_t)(n0 + r) * Kt + kt + sc * 8,
                    &Bs[buf][(size_t)dst * 8]);
        }
    };
    // layers 2/3 A staging: reg load, BN+ReLU, swizzled ds_write (2 loads/thread)
    auto loadA_regs = [&](int kt) {
        #pragma unroll
        for (int i = 0; i < 2; ++i) {
            int v = tid + i * 512;
            int r = v >> 3, gc = v & 7;
            int k = kt + gc * 8;
            Ar[i] = (k < Kreal) ? *(const short8v*)(A + (size_t)(m0 + r) * lda + k) : zero8;
        }
    };
    auto writeA_lds = [&](int buf, int kt) {
        #pragma unroll
        for (int i = 0; i < 2; ++i) {
            int v = tid + i * 512;
            int r = v >> 3, gc = v & 7;
            short8v val = Ar[i];
            #pragma unroll
            for (int e = 0; e < 8; ++e) {
                int k = kt + gc * 8 + e;
                float x = bf2f((unsigned short)val[e]);
                val[e] = (short)f2bf(fmaxf(x * ssc[k] + ssh[k], 0.f));
            }
            *(short8v*)(&As[buf][r * BK + ((gc ^ (r & 7)) * 8)]) = val;
        }
    };

    float4v acc[2][7];
    #pragma unroll
    for (int i = 0; i < 2; ++i)
        #pragma unroll
        for (int f = 0; f < 7; ++f)
            acc[i][f] = (float4v){0.f, 0.f, 0.f, 0.f};

    // prologue: stage tile 0, full drain (once)
    if (FUSE_BN) loadA_regs(0); else stageA_g(0, 0);
    stageB(0, 0);
    __syncthreads();                       // ssc/ssh + scol ready; tile-0 DMA drained
    if (FUSE_BN) { writeA_lds(0, 0); __syncthreads(); }

    int nsteps = Kt / BK;
    int buf = 0;
    for (int s = 0; s < nsteps; ++s) {
        bool more = (s + 1 < nsteps);
        if (more) {
            if (FUSE_BN) loadA_regs((s + 1) * BK); else stageA_g(buf ^ 1, (s + 1) * BK);
            stageB(buf ^ 1, (s + 1) * BK);
        }
        if (more) bar_vm6(); else bar_vm0();   // barrier #1: buf staged & published
        __builtin_amdgcn_s_setprio(1);
        #pragma unroll
        for (int kk = 0; kk < BK; kk += 32) {
            int kc = kk >> 3;              // 0 or 4
            short8v af[2], bfr[7];
            #pragma unroll
            for (int i = 0; i < 2; ++i) {
                int r = mi * 32 + i * 16 + l16;
                af[i] = *(const short8v*)(&As[buf][r * BK + (((quad + kc) ^ (r & 7)) * 8)]);
            }
            #pragma unroll
            for (int f = 0; f < 7; ++f) {
                int r = nj * 112 + f * 16 + l16;
                bfr[f] = *(const short8v*)(&Bs[buf][r * BK + (((quad + kc) ^ (r & 7)) * 8)]);
            }
            #pragma unroll
            for (int i = 0; i < 2; ++i)
                #pragma unroll
                for (int f = 0; f < 7; ++f)
                    acc[i][f] = __builtin_amdgcn_mfma_f32_16x16x32_bf16(af[i], bfr[f], acc[i][f], 0, 0, 0);
        }
        __builtin_amdgcn_s_setprio(0);
        if (FUSE_BN && more) writeA_lds(buf ^ 1, (s + 1) * BK);  // hid under next wait
        bar_lgkm();                        // barrier #2: readers of buf done; ds_writes out
        buf ^= 1;
    }

    // epilogue: store C + per-column stats. C/D layout: col=lane&15, row=quad*4+reg
    #pragma unroll
    for (int f = 0; f < 7; ++f) {
        int lc = nj * 112 + f * 16 + l16;
        int col = n0 + lc;
        float bv = (col < HID) ? bias[col] : 0.f;
        float s = 0.f, q = 0.f;
        #pragma unroll
        for (int i = 0; i < 2; ++i) {
            #pragma unroll
            for (int r = 0; r < 4; ++r) {
                int row = m0 + mi * 32 + i * 16 + quad * 4 + r;
                float v = acc[i][f][r] + bv;
                if (col < HID) C[(size_t)row * HID + col] = f2bf(v);
                s += v;
                q += v * v;
            }
        }
        s += __shfl_down(s, 32, 64); s += __shfl_down(s, 16, 64);
        q += __shfl_down(q, 32, 64); q += __shfl_down(q, 16, 64);
        if (lane < 16) {
            atomicAdd(&scol[lc], s);
            atomicAdd(&qcol[lc], q);
        }
    }
    __syncthreads();
    if (tid < BNT) {
        int col = n0 + tid;
        if (col < HID) {
            atomicAdd(&sums[col], scol[tid]);
            atomicAdd(&sums[HID + col], qcol[tid]);
        }
    }
}

// ---------------- final: finalize3 (in-block, strided fill) + BN3+ReLU+rowsum --------------
__global__ __launch_bounds__(256) void final_kernel(const unsigned short* __restrict__ H3,
                                                    const float* __restrict__ sums,
                                                    const float* __restrict__ g,
                                                    const float* __restrict__ bt,
                                                    const float* __restrict__ f12,
                                                    const float* __restrict__ bias,
                                                    float* __restrict__ out) {
    __shared__ float ssc[HID], ssh[HID];
    int tid = threadIdx.x;
    const float invN = 1.f / (float)NROWS;
    for (int j = tid; j < HID; j += 256) {
        float mu = sums[j] * invN;
        float var = sums[HID + j] * invN - mu * mu;
        float rstd = rsqrtf(var + BN_EPS);
        float sc = g[j] * rstd;
        ssc[j] = sc;
        ssh[j] = bt[j] - mu * sc;
    }
    __syncthreads();
    int wave = tid >> 6, lane = tid & 63;
    int n = blockIdx.x * 4 + wave;
    float acc = 0.f;
    if (lane < 50) {
        short8v v = *(const short8v*)(H3 + (size_t)n * HID + lane * 8);
        #pragma unroll
        for (int e = 0; e < 8; ++e) {
            int k = lane * 8 + e;
            float x = bf2f((unsigned short)v[e]) * ssc[k] + ssh[k];
            acc += fmaxf(x, 0.f);
        }
    }
    #pragma unroll
    for (int o = 32; o; o >>= 1) acc += __shfl_down(acc, o, 64);
    if (lane == 0) out[n] = acc + f12[n] + bias[0];
}

// ---------------- launch ----------------
extern "C" void kernel_launch(void* const* d_in, const int* in_sizes, int n_in,
                              void* d_out, int out_size, void* d_ws, size_t ws_size,
                              hipStream_t stream) {
    const int* Xi = (const int*)d_in[0];
    const float* Xv = (const float*)d_in[1];
    const float* emb1 = (const float*)d_in[2];
    const float* emb2 = (const float*)d_in[3];
    const float* W1 = (const float*)d_in[4];
    const float* b1 = (const float*)d_in[5];
    const float* g1 = (const float*)d_in[6];
    const float* bt1 = (const float*)d_in[7];
    const float* W2 = (const float*)d_in[8];
    const float* b2 = (const float*)d_in[9];
    const float* g2 = (const float*)d_in[10];
    const float* bt2 = (const float*)d_in[11];
    const float* W3 = (const float*)d_in[12];
    const float* b3 = (const float*)d_in[13];
    const float* g3 = (const float*)d_in[14];
    const float* bt3 = (const float*)d_in[15];
    const float* bias = (const float*)d_in[16];

    char* ws = (char*)d_ws;
    size_t o_f12 = 0;
    size_t o_h0  = 65536;
    size_t o_h1  = o_h0 + (size_t)NROWS * K1T * 2;
    size_t o_w1  = o_h1 + (size_t)NROWS * HID * 2;
    size_t o_w2  = o_w1 + (size_t)448 * K1T * 2;
    size_t o_w3  = o_w2 + (size_t)448 * K2T * 2;
    size_t o_sums = o_w3 + (size_t)448 * K2T * 2;

    float* f12 = (float*)(ws + o_f12);
    unsigned short* h0 = (unsigned short*)(ws + o_h0);
    unsigned short* h1 = (unsigned short*)(ws + o_h1);
    unsigned short* h2 = (unsigned short*)(ws + o_h0);   // alias: h0 dead after gemm1
    unsigned short* h3 = (unsigned short*)(ws + o_h1);   // alias: h1 dead after gemm2
    unsigned short* w1b = (unsigned short*)(ws + o_w1);
    unsigned short* w2b = (unsigned short*)(ws + o_w2);
    unsigned short* w3b = (unsigned short*)(ws + o_w3);
    float* sums1 = (float*)(ws + o_sums);
    float* sums2 = sums1 + 800;
    float* sums3 = sums2 + 800;
    float* out = (float*)d_out;

    prep_kernel<<<EMB_BLOCKS + CVT_BLOCKS + 1, 256, 0, stream>>>(
        Xi, Xv, emb1, emb2, W1, W2, W3, h0, f12, w1b, w2b, w3b, sums1);

    dim3 ggrid(NROWS / BM, 2);

    gemm_kernel<false><<<ggrid, 512, 0, stream>>>(h0, K1T, K1T, K1T, w1b, b1,
                                                  nullptr, nullptr, nullptr, h1, sums1);
    gemm_kernel<true><<<ggrid, 512, 0, stream>>>(h1, HID, HID, K2T, w2b, b2,
                                                 sums1, g1, bt1, h2, sums2);
    gemm_kernel<true><<<ggrid, 512, 0, stream>>>(h2, HID, HID, K2T, w3b, b3,
                                                 sums2, g2, bt2, h3, sums3);
    final_kernel<<<NROWS / 4, 256, 0, stream>>>(h3, sums3, g3, bt3, f12, bias, out);
}